// Round 1
// baseline (1139.622 us; speedup 1.0000x reference)
//
#include <hip/hip_runtime.h>
#include <hip/hip_bf16.h>

namespace {

constexpr int kV = 50000;
constexpr int kD = 128;
constexpr int kB = 512;
constexpr int kT = 256;
constexpr int kU = 256;

typedef __attribute__((ext_vector_type(8))) short  bfrag8;   // 8 x bf16 -> 4 VGPR (MFMA operand)
typedef __attribute__((ext_vector_type(4))) float  facc4;    // MFMA accumulator
typedef __attribute__((ext_vector_type(4))) float  vfloat4;
typedef __attribute__((ext_vector_type(4))) int    vint4;

__device__ __forceinline__ unsigned short f2bf(float f) {
  return __builtin_bit_cast(unsigned short, __float2bfloat16(f));
}
__device__ __forceinline__ float bf2f(unsigned short u) {
  unsigned int i = ((unsigned int)u) << 16;
  return __builtin_bit_cast(float, i);
}
__device__ __forceinline__ float tanh_fast(float x) {
  x = fminf(12.f, fmaxf(-12.f, x));
  float e = __expf(2.f * x);
  return __fdividef(e - 1.f, e + 1.f);
}

// ---------------------------------------------------------------------------
// Pre-pass: EK[v][u] = bf16( emb[v][:] @ k0[:][u] + b0[u] )   (V x 256, bf16)
// grid: ceil(V/128) blocks x 256 threads
// ---------------------------------------------------------------------------
__global__ __launch_bounds__(256) void ek_prepass(
    const float* __restrict__ emb, const float* __restrict__ k0,
    const float* __restrict__ b0, __hip_bfloat16* __restrict__ EK)
{
  // k0 transposed: [u][k], row pad to 136 elems (272 B, 16B aligned)
  __shared__ __align__(16) unsigned short k0t[256 * 136];
  const int tid = threadIdx.x;

  for (int it = 0; it < 32; ++it) {                 // 128*256 fp32, coalesced
    int e = it * 1024 + tid * 4;
    int k = e >> 8, c = e & 255;
    vfloat4 wv = *(const vfloat4*)(k0 + e);
    #pragma unroll
    for (int i = 0; i < 4; ++i) k0t[(c + i) * 136 + k] = f2bf(wv[i]);
  }
  __syncthreads();

  const int l = tid & 63, w = tid >> 6;
  const int lr = l & 15, q = l >> 4;

  bfrag8 Fb[4][4];                                  // B-frags: k0[k][col]
  #pragma unroll
  for (int ut = 0; ut < 4; ++ut) {
    #pragma unroll
    for (int kt = 0; kt < 4; ++kt) {
      int col = w * 64 + ut * 16 + lr;
      Fb[ut][kt] = *(const bfrag8*)((const char*)k0t + col * 272 + kt * 64 + q * 16);
    }
  }

  float b0v[4];
  #pragma unroll
  for (int ut = 0; ut < 4; ++ut) b0v[ut] = b0[w * 64 + ut * 16 + lr];

  const int v0 = blockIdx.x * 128;
  for (int mt = 0; mt < 8; ++mt) {
    int vr = v0 + mt * 16 + lr;
    int vc = vr < kV ? vr : kV - 1;
    bfrag8 Fa[4];                                   // A-frags: emb rows (global direct)
    #pragma unroll
    for (int kt = 0; kt < 4; ++kt) {
      const vfloat4* p = (const vfloat4*)(emb + vc * kD + kt * 32 + q * 8);
      vfloat4 x0 = p[0], x1 = p[1];
      bfrag8 a;
      #pragma unroll
      for (int i = 0; i < 4; ++i) {
        a[i]     = (short)f2bf(x0[i]);
        a[i + 4] = (short)f2bf(x1[i]);
      }
      Fa[kt] = a;
    }
    facc4 acc[4];
    #pragma unroll
    for (int ut = 0; ut < 4; ++ut) {
      facc4 ini = {b0v[ut], b0v[ut], b0v[ut], b0v[ut]};
      acc[ut] = ini;
    }
    #pragma unroll
    for (int kt = 0; kt < 4; ++kt) {
      #pragma unroll
      for (int ut = 0; ut < 4; ++ut)
        acc[ut] = __builtin_amdgcn_mfma_f32_16x16x32_bf16(Fa[kt], Fb[ut][kt], acc[ut], 0, 0, 0);
    }
    #pragma unroll
    for (int ut = 0; ut < 4; ++ut) {
      #pragma unroll
      for (int r = 0; r < 4; ++r) {
        int row = v0 + mt * 16 + q * 4 + r;         // C: col=lane&15, row=(lane>>4)*4+r
        if (row < kV)
          EK[row * kU + w * 64 + ut * 16 + lr] = __float2bfloat16(acc[ut][r]);
      }
    }
  }
}

// ---------------------------------------------------------------------------
// Persistent RNN kernel: 32 blocks x 256 threads; block b owns batch rows
// [16b, 16b+16). Wave w owns output cols [64w, 64w+64) (4 MFMA col-tiles).
// Weights live in registers (B-frags). h0/h1 exchanged via swizzled LDS,
// double-buffered -> ONE __syncthreads per step.
// ---------------------------------------------------------------------------
__global__ __launch_bounds__(256, 1) void rnn_persist(
    const int* __restrict__ inputs, const __hip_bfloat16* __restrict__ EK,
    const float* __restrict__ rk0g, const float* __restrict__ k1g,
    const float* __restrict__ rk1g, const float* __restrict__ b1,
    const float* __restrict__ wo, const float* __restrict__ bo,
    float* __restrict__ out)
{
  __shared__ __align__(16) unsigned short h0s[2][16 * 256];  // swizzled bf16
  __shared__ __align__(16) unsigned short h1s[2][16 * 256];
  __shared__ __align__(16) unsigned short eks[2][16 * 256];  // EK gather staging
  __shared__ __align__(16) int idxs[16 * 256];               // [row][t]
  __shared__ __align__(16) unsigned short wT[256 * 72];      // weight staging [col][k], pad 72

  const int tid = threadIdx.x, blk = blockIdx.x;
  const int l = tid & 63, w = tid >> 6;
  const int lr = l & 15, q = l >> 4;

  // ---- load this block's indices (rows are contiguous: linear copy) ----
  #pragma unroll
  for (int it = 0; it < 4; ++it) {
    int e = it * 1024 + tid * 4;
    *(vint4*)(idxs + e) = *(const vint4*)(inputs + blk * 4096 + e);
  }
  // ---- zero initial h state (buffers [0]) ----
  {
    bfrag8 z = {0, 0, 0, 0, 0, 0, 0, 0};
    #pragma unroll
    for (int it = 0; it < 2; ++it) {
      int off = it * 4096 + tid * 16;
      *(bfrag8*)((char*)h0s[0] + off) = z;
      *(bfrag8*)((char*)h1s[0] + off) = z;
    }
  }

  // ---- load recurrent-weight fragments into registers (384 VGPR/wave) ----
  bfrag8 Frk0[4][8], Fk1[4][8], Frk1[4][8];

#define STAGE_MAT(SRC, DST)                                                    \
  _Pragma("unroll")                                                            \
  for (int c = 0; c < 4; ++c) {                                                \
    __syncthreads();                                                           \
    for (int it = 0; it < 16; ++it) {                                          \
      int e = it * 1024 + tid * 4;                                             \
      int k = e >> 8, col = e & 255;                                           \
      vfloat4 wv = *(const vfloat4*)(SRC + (c * 64 + k) * 256 + col);          \
      _Pragma("unroll")                                                        \
      for (int i = 0; i < 4; ++i) wT[(col + i) * 72 + k] = f2bf(wv[i]);        \
    }                                                                          \
    __syncthreads();                                                           \
    _Pragma("unroll")                                                          \
    for (int ut = 0; ut < 4; ++ut) {                                           \
      _Pragma("unroll")                                                        \
      for (int kk = 0; kk < 2; ++kk)                                           \
        DST[ut][c * 2 + kk] = *(const bfrag8*)((const char*)wT +               \
            (w * 64 + ut * 16 + lr) * 144 + kk * 64 + q * 16);                 \
    }                                                                          \
  }

  STAGE_MAT(rk0g, Frk0);
  STAGE_MAT(k1g, Fk1);
  STAGE_MAT(rk1g, Frk1);
#undef STAGE_MAT

  float b1v[4];
  #pragma unroll
  for (int ut = 0; ut < 4; ++ut) b1v[ut] = b1[w * 64 + ut * 16 + lr];

  // EK gather: each thread moves two 16B chunks of the 8KB step tile
  const int pc0 = tid, pc1 = tid + 256;
  const int pr0 = pc0 >> 5, pp0 = pc0 & 31;
  const int pr1 = pc1 >> 5, pp1 = pc1 & 31;
  const int ekw0 = pr0 * 512 + ((pp0 * 16) ^ ((pr0 & 7) << 4));
  const int ekw1 = pr1 * 512 + ((pp1 * 16) ^ ((pr1 & 7) << 4));
  const int sA = (lr & 7) << 4;   // A-fragment read swizzle (row = lr)

  // ---- prologue: fetch EK rows for t=0 into eks[0] ----
  {
    vint4 g0 = *(const vint4*)((const char*)EK + (size_t)idxs[pr0 * 256] * 512 + pp0 * 16);
    vint4 g1 = *(const vint4*)((const char*)EK + (size_t)idxs[pr1 * 256] * 512 + pp1 * 16);
    *(vint4*)((char*)eks[0] + ekw0) = g0;
    *(vint4*)((char*)eks[0] + ekw1) = g1;
  }
  __syncthreads();

  for (int t = 0; t < kT; ++t) {
    const int cur = t & 1, nxt = cur ^ 1;

    // prefetch EK rows for t+1 (hidden under GEMM0)
    int tn = (t + 1 < kT) ? t + 1 : kT - 1;
    vint4 g0 = *(const vint4*)((const char*)EK + (size_t)idxs[pr0 * 256 + tn] * 512 + pp0 * 16);
    vint4 g1 = *(const vint4*)((const char*)EK + (size_t)idxs[pr1 * 256 + tn] * 512 + pp1 * 16);

    // ---- GEMM0: h0' = tanh(EK[x_t] + h0 @ rk0) ----
    facc4 acc[4];
    #pragma unroll
    for (int ut = 0; ut < 4; ++ut) {
      #pragma unroll
      for (int r = 0; r < 4; ++r) {
        int rw = q * 4 + r;
        int byte = rw * 512 + ((((w * 64 + ut * 16 + lr) * 2)) ^ ((rw & 7) << 4));
        acc[ut][r] = bf2f(*(const unsigned short*)((const char*)eks[cur] + byte));
      }
    }
    #pragma unroll
    for (int kt = 0; kt < 8; ++kt) {
      bfrag8 a = *(const bfrag8*)((const char*)h0s[cur] + lr * 512 + ((kt * 64 + q * 16) ^ sA));
      #pragma unroll
      for (int ut = 0; ut < 4; ++ut)
        acc[ut] = __builtin_amdgcn_mfma_f32_16x16x32_bf16(a, Frk0[ut][kt], acc[ut], 0, 0, 0);
    }
    unsigned short h0n[4][4];
    #pragma unroll
    for (int ut = 0; ut < 4; ++ut) {
      #pragma unroll
      for (int r = 0; r < 4; ++r) h0n[ut][r] = f2bf(tanh_fast(acc[ut][r]));
    }

    // write h0' (other buffer) and next EK tile; all old readers are >=1 barrier back
    #pragma unroll
    for (int ut = 0; ut < 4; ++ut) {
      #pragma unroll
      for (int r = 0; r < 4; ++r) {
        int rw = q * 4 + r;
        int byte = rw * 512 + ((((w * 64 + ut * 16 + lr) * 2)) ^ ((rw & 7) << 4));
        *(unsigned short*)((char*)h0s[nxt] + byte) = h0n[ut][r];
      }
    }
    *(vint4*)((char*)eks[nxt] + ekw0) = g0;
    *(vint4*)((char*)eks[nxt] + ekw1) = g1;

    __syncthreads();   // the single per-step barrier

    // ---- GEMM1: h1' = tanh(b1 + h0' @ k1 + h1 @ rk1) ----
    facc4 acc1[4];
    #pragma unroll
    for (int ut = 0; ut < 4; ++ut) {
      facc4 ini = {b1v[ut], b1v[ut], b1v[ut], b1v[ut]};
      acc1[ut] = ini;
    }
    #pragma unroll
    for (int kt = 0; kt < 8; ++kt) {
      bfrag8 a0 = *(const bfrag8*)((const char*)h0s[nxt] + lr * 512 + ((kt * 64 + q * 16) ^ sA));
      bfrag8 a1 = *(const bfrag8*)((const char*)h1s[cur] + lr * 512 + ((kt * 64 + q * 16) ^ sA));
      #pragma unroll
      for (int ut = 0; ut < 4; ++ut) {
        acc1[ut] = __builtin_amdgcn_mfma_f32_16x16x32_bf16(a0, Fk1[ut][kt], acc1[ut], 0, 0, 0);
        acc1[ut] = __builtin_amdgcn_mfma_f32_16x16x32_bf16(a1, Frk1[ut][kt], acc1[ut], 0, 0, 0);
      }
    }
    #pragma unroll
    for (int ut = 0; ut < 4; ++ut) {
      #pragma unroll
      for (int r = 0; r < 4; ++r) {
        int rw = q * 4 + r;
        int byte = rw * 512 + ((((w * 64 + ut * 16 + lr) * 2)) ^ ((rw & 7) << 4));
        *(unsigned short*)((char*)h1s[nxt] + byte) = f2bf(tanh_fast(acc1[ut][r]));
      }
    }
  }
  __syncthreads();

  // ---- epilogue: out = sigmoid(h1_T @ wo + bo); final h1 is in h1s[0] ----
  if (w == 0) {
    float dot = 0.f;
    #pragma unroll
    for (int c8 = 0; c8 < 8; ++c8) {
      int colb = (q * 64 + c8 * 8) * 2;
      bfrag8 hv = *(const bfrag8*)((const char*)h1s[0] + lr * 512 + (colb ^ sA));
      #pragma unroll
      for (int j = 0; j < 8; ++j)
        dot += bf2f((unsigned short)hv[j]) * wo[q * 64 + c8 * 8 + j];
    }
    dot += __shfl_xor(dot, 16);
    dot += __shfl_xor(dot, 32);
    if (l < 16) {
      float z = dot + bo[0];
      z = fminf(30.f, fmaxf(-30.f, z));
      out[blk * 16 + lr] = __fdividef(1.f, 1.f + __expf(-z));
    }
  }
}

}  // namespace

extern "C" void kernel_launch(void* const* d_in, const int* in_sizes, int n_in,
                              void* d_out, int out_size, void* d_ws, size_t ws_size,
                              hipStream_t stream) {
  const int*   inputs = (const int*)  d_in[0];
  const float* emb    = (const float*)d_in[1];
  const float* k0     = (const float*)d_in[2];
  const float* rk0    = (const float*)d_in[3];
  const float* b0     = (const float*)d_in[4];
  const float* k1     = (const float*)d_in[5];
  const float* rk1    = (const float*)d_in[6];
  const float* b1     = (const float*)d_in[7];
  const float* wo     = (const float*)d_in[8];
  const float* bo     = (const float*)d_in[9];
  float* out = (float*)d_out;

  __hip_bfloat16* EK = (__hip_bfloat16*)d_ws;          // V*U bf16 = 25.6 MB
  if (ws_size < (size_t)kV * kU * sizeof(__hip_bfloat16)) return;

  ek_prepass<<<(kV + 127) / 128, 256, 0, stream>>>(emb, k0, b0, EK);
  rnn_persist<<<kB / 16, 256, 0, stream>>>(inputs, EK, rk0, k1, rk1, b1, wo, bo, out);
}